// Round 2
// 4551.491 us; speedup vs baseline: 2.5885x; 2.5885x over previous
//
#include <hip/hip_runtime.h>

typedef unsigned short u16;

#define DEVFN static __device__ __forceinline__

constexpr int Sq = 2048, Dm = 1024, NH = 16, HDim = 64, NE = 8, FHid = 4096;

typedef __attribute__((ext_vector_type(8))) short bf16x8;
typedef __attribute__((ext_vector_type(4))) float f32x4;

DEVFN float b2f(u16 u) { return __uint_as_float(((unsigned)u) << 16); }
// round-to-nearest-even f32 -> bf16
DEVFN u16 f2b(float f) {
  unsigned u = __float_as_uint(f);
  return (u16)((u + 0x7fffu + ((u >> 16) & 1u)) >> 16);
}
DEVFN float gelu_f(float x) {
  float y = 0.7978845608028654f * (x + 0.044715f * x * x * x);
  float t = 1.0f - 2.0f / (__expf(2.0f * y) + 1.0f);
  return 0.5f * x * (1.0f + t);
}

DEVFN void gload16(const u16* g, u16* l) {
  __builtin_amdgcn_global_load_lds((const __attribute__((address_space(1))) void*)g,
                                   (__attribute__((address_space(3))) void*)l, 16, 0, 0);
}

// ---------------- input dtype detector: flag=1 if inputs are f32 ----------------
__global__ __launch_bounds__(256) void detect_k(const u16* __restrict__ x, int* __restrict__ flag) {
  int t = threadIdx.x;
  float mx = 0.f;
  for (int i = t; i < 4096; i += 256) mx = fmaxf(mx, fabsf(b2f(x[i])));
#pragma unroll
  for (int m = 32; m; m >>= 1) mx = fmaxf(mx, __shfl_xor(mx, m, 64));
  __shared__ float red[4];
  if ((t & 63) == 0) red[t >> 6] = mx;
  __syncthreads();
  if (t == 0) {
    float m2 = fmaxf(fmaxf(red[0], red[1]), fmaxf(red[2], red[3]));
    flag[0] = (m2 > 1e6f) ? 1 : 0;
  }
}

// ---- rmsnorm: ONE WAVE per row, shuffle reduction.  (VERBATIM from passing baseline)
template <int INM, int RESM>
__global__ __launch_bounds__(64) void rmsnorm2_k(const void* __restrict__ inp, const void* __restrict__ g,
                                                 const void* __restrict__ resp, float* __restrict__ out1,
                                                 const int* __restrict__ dflag) {
  int isf = dflag[0];
  int row = blockIdx.x, t = threadIdx.x;  // 64 threads
  long rb = (long)row * Dm;
  float v[16];
#pragma unroll
  for (int j = 0; j < 4; j++) {
    long o = rb + t * 4 + j * 256;
    if (INM == 0 || isf) {
      float4 f = *((const float4*)((const float*)inp + o));
      v[4 * j] = f.x; v[4 * j + 1] = f.y; v[4 * j + 2] = f.z; v[4 * j + 3] = f.w;
    } else {
      ushort4 u = *((const ushort4*)((const u16*)inp + o));
      v[4 * j] = b2f(u.x); v[4 * j + 1] = b2f(u.y); v[4 * j + 2] = b2f(u.z); v[4 * j + 3] = b2f(u.w);
    }
  }
  float ss = 0.f;
#pragma unroll
  for (int j = 0; j < 16; j++) ss += v[j] * v[j];
#pragma unroll
  for (int m = 32; m; m >>= 1) ss += __shfl_xor(ss, m, 64);
  float sc = rsqrtf(ss * (1.0f / Dm) + 1e-5f);
#pragma unroll
  for (int j = 0; j < 4; j++) {
    long o = rb + t * 4 + j * 256;
    int go = t * 4 + j * 256;
    float gf[4];
    if (isf) {
      float4 gv = *((const float4*)((const float*)g + go));
      gf[0] = gv.x; gf[1] = gv.y; gf[2] = gv.z; gf[3] = gv.w;
    } else {
      ushort4 gu = *((const ushort4*)((const u16*)g + go));
      gf[0] = b2f(gu.x); gf[1] = b2f(gu.y); gf[2] = b2f(gu.z); gf[3] = b2f(gu.w);
    }
    float o4[4];
#pragma unroll
    for (int q = 0; q < 4; q++) o4[q] = v[4 * j + q] * sc * gf[q];
    if constexpr (RESM == 1) {
      float4 rf = *((const float4*)((const float*)resp + o));
      o4[0] += rf.x; o4[1] += rf.y; o4[2] += rf.z; o4[3] += rf.w;
    } else if constexpr (RESM == 2) {
      if (isf) {
        float4 rf = *((const float4*)((const float*)resp + o));
        o4[0] += rf.x; o4[1] += rf.y; o4[2] += rf.z; o4[3] += rf.w;
      } else {
        ushort4 ru = *((const ushort4*)((const u16*)resp + o));
        o4[0] += b2f(ru.x); o4[1] += b2f(ru.y); o4[2] += b2f(ru.z); o4[3] += b2f(ru.w);
      }
    }
    float4 of;
    of.x = o4[0]; of.y = o4[1]; of.z = o4[2]; of.w = o4[3];
    *((float4*)(out1 + o)) = of;
  }
}

// ---------------- naive tiled f32 GEMM  (VERBATIM from passing baseline; used pre-router only) ---
template <int OP>
__global__ __launch_bounds__(256) void gemm_nn_k(
    const float* __restrict__ A, const void* __restrict__ Braw, long boff,
    float* __restrict__ C, int M, int N, int K,
    const float* __restrict__ wfull, int eidx, const int* __restrict__ dflag) {
  int isf = dflag[0];
  const float* Bf = (const float*)Braw;
  const u16* Bh = (const u16*)Braw;
  int t = threadIdx.x;
  int m0 = blockIdx.y * 64, n0 = blockIdx.x * 64;

  __shared__ float As[64][17];
  __shared__ float Bs[16][65];
  __shared__ int anyw;

  if constexpr (OP >= 1) {
    if (t == 0) anyw = 0;
    __syncthreads();
    if (t < 64) {
      if (wfull[(long)(m0 + t) * 8 + eidx] != 0.f) anyw = 1;
    }
    __syncthreads();
    if (!anyw) return;
  }

  int ty = t >> 4, tx = t & 15;
  float acc[4][4];
#pragma unroll
  for (int i = 0; i < 4; i++)
#pragma unroll
    for (int j = 0; j < 4; j++) acc[i][j] = 0.f;

  for (int k0 = 0; k0 < K; k0 += 16) {
    __syncthreads();
#pragma unroll
    for (int i = 0; i < 4; i++) {
      int idx = t + i * 256;
      int ar = idx >> 4, ac = idx & 15;
      As[ar][ac] = A[(long)(m0 + ar) * K + k0 + ac];
      int br = idx >> 6, bc = idx & 63;
      long bi = boff + (long)(k0 + br) * N + n0 + bc;
      Bs[br][bc] = isf ? Bf[bi] : b2f(Bh[bi]);
    }
    __syncthreads();
#pragma unroll
    for (int kk = 0; kk < 16; kk++) {
      float a[4], b[4];
#pragma unroll
      for (int i = 0; i < 4; i++) a[i] = As[ty * 4 + i][kk];
#pragma unroll
      for (int j = 0; j < 4; j++) b[j] = Bs[kk][tx * 4 + j];
#pragma unroll
      for (int i = 0; i < 4; i++)
#pragma unroll
        for (int j = 0; j < 4; j++) acc[i][j] += a[i] * b[j];
    }
  }
#pragma unroll
  for (int i = 0; i < 4; i++) {
    int row = m0 + ty * 4 + i;
#pragma unroll
    for (int j = 0; j < 4; j++) {
      int col = n0 + tx * 4 + j;
      long cidx = (long)row * N + col;
      float val = acc[i][j];
      if constexpr (OP == 0) C[cidx] = val;
      else if constexpr (OP == 1) C[cidx] = gelu_f(val);
      else C[cidx] += wfull[(long)row * 8 + eidx] * val;
    }
  }
}

// ---------------- plain-f32 attention  (VERBATIM from passing baseline) --------------
__global__ __launch_bounds__(256) void attn_f32_k(
    const float* __restrict__ Qf, const float* __restrict__ Kf, const float* __restrict__ Vf,
    float* __restrict__ Of) {
  int qb = blockIdx.x, h = blockIdx.y;
  int t = threadIdx.x;
  int qr = t >> 2;
  int sub = t & 3;
  __shared__ float Ks[64][65];
  __shared__ float Vs[64][65];
  int qrow = qb * 64 + qr;
  const float* qp = Qf + (long)qrow * Dm + h * HDim + sub * 16;
  float qfr[16];
#pragma unroll
  for (int j = 0; j < 16; j += 4) {
    float4 v = *(const float4*)(qp + j);
    qfr[j] = v.x; qfr[j + 1] = v.y; qfr[j + 2] = v.z; qfr[j + 3] = v.w;
  }
  float o[16];
#pragma unroll
  for (int j = 0; j < 16; j++) o[j] = 0.f;
  float m_i = -3e38f, l_i = 0.f;

  for (int kb = 0; kb < Sq / 64; kb++) {
    __syncthreads();
#pragma unroll
    for (int i = 0; i < 2; i++) {
      int idx = t + i * 256;
      int r = idx >> 3, c8 = (idx & 7) * 8;
      const float* kp = Kf + (long)(kb * 64 + r) * HDim + c8;
      float4 a = *(const float4*)(kp);
      float4 b = *(const float4*)(kp + 4);
      Ks[r][c8 + 0] = a.x; Ks[r][c8 + 1] = a.y; Ks[r][c8 + 2] = a.z; Ks[r][c8 + 3] = a.w;
      Ks[r][c8 + 4] = b.x; Ks[r][c8 + 5] = b.y; Ks[r][c8 + 6] = b.z; Ks[r][c8 + 7] = b.w;
      const float* vp = Vf + (long)(kb * 64 + r) * HDim + c8;
      float4 c = *(const float4*)(vp);
      float4 d = *(const float4*)(vp + 4);
      Vs[r][c8 + 0] = c.x; Vs[r][c8 + 1] = c.y; Vs[r][c8 + 2] = c.z; Vs[r][c8 + 3] = c.w;
      Vs[r][c8 + 4] = d.x; Vs[r][c8 + 5] = d.y; Vs[r][c8 + 6] = d.z; Vs[r][c8 + 7] = d.w;
    }
    __syncthreads();
    float s[64];
#pragma unroll
    for (int j = 0; j < 64; j++) {
      float acc = 0.f;
#pragma unroll
      for (int d = 0; d < 16; d++) acc += qfr[d] * Ks[j][sub * 16 + d];
      s[j] = acc;
    }
#pragma unroll
    for (int j = 0; j < 64; j++) {
      float v = s[j];
      v += __shfl_xor(v, 1, 64);
      v += __shfl_xor(v, 2, 64);
      s[j] = v * 0.125f;
    }
    float mx = s[0];
#pragma unroll
    for (int j = 1; j < 64; j++) mx = fmaxf(mx, s[j]);
    float mn = fmaxf(m_i, mx);
    float alpha = __expf(m_i - mn);
    m_i = mn;
    float ps = 0.f;
#pragma unroll
    for (int j = 0; j < 64; j++) {
      s[j] = __expf(s[j] - mn);
      ps += s[j];
    }
    l_i = l_i * alpha + ps;
#pragma unroll
    for (int d = 0; d < 16; d++) o[d] *= alpha;
#pragma unroll
    for (int j = 0; j < 64; j++)
#pragma unroll
      for (int d = 0; d < 16; d++) o[d] += s[j] * Vs[j][sub * 16 + d];
  }
  float inv = 1.0f / l_i;
#pragma unroll
  for (int d = 0; d < 16; d++)
    Of[(long)qrow * Dm + h * HDim + sub * 16 + d] = o[d] * inv;
}

// ---- router: one thread per token; top-2 from logits  (VERBATIM from passing baseline)
__global__ __launch_bounds__(256) void router2_k(const float* __restrict__ h2, const void* __restrict__ Wr,
                                                 float* __restrict__ probs_out, float* __restrict__ wfull,
                                                 const int* __restrict__ dflag) {
  int isf = dflag[0];
  int tok = blockIdx.x * 256 + threadIdx.x;
  if (tok >= Sq) return;
  const float* hrow = h2 + (long)tok * Dm;
  float acc[8] = {0, 0, 0, 0, 0, 0, 0, 0};
  for (int i = 0; i < Dm; i++) {
    float hv = hrow[i];
    if (isf) {
      const float* wr = (const float*)Wr + (long)i * 8;
#pragma unroll
      for (int e = 0; e < 8; e++) acc[e] += hv * wr[e];
    } else {
      const u16* wr = (const u16*)Wr + (long)i * 8;
#pragma unroll
      for (int e = 0; e < 8; e++) acc[e] += hv * b2f(wr[e]);
    }
  }
  int i1 = 0;
#pragma unroll
  for (int e = 1; e < 8; e++)
    if (acc[e] > acc[i1]) i1 = e;
  int i2 = (i1 == 0) ? 1 : 0;
#pragma unroll
  for (int e = 0; e < 8; e++)
    if (e != i1 && acc[e] > acc[i2]) i2 = e;
  float mx = acc[i1];
  float pr[8], s = 0.f;
#pragma unroll
  for (int e = 0; e < 8; e++) { pr[e] = expf(acc[e] - mx); s += pr[e]; }
  float inv = 1.0f / s;
#pragma unroll
  for (int e = 0; e < 8; e++) {
    float pe = pr[e] * inv;
    probs_out[(long)tok * 8 + e] = pe;
    wfull[(long)tok * 8 + e] = (e == i1 || e == i2) ? pe : 0.f;
  }
}

// ---- split f32 -> (hi, lo) bf16 pair; hi+lo represents f32 to ~2^-17 relative ----
__global__ __launch_bounds__(256) void split_pair_k(const float* __restrict__ in, u16* __restrict__ hi,
                                                    u16* __restrict__ lo, int n4) {
  int i = blockIdx.x * 256 + threadIdx.x;
  if (i >= n4) return;
  float4 v = ((const float4*)in)[i];
  ushort4 h, l;
  h.x = f2b(v.x); l.x = f2b(v.x - b2f(h.x));
  h.y = f2b(v.y); l.y = f2b(v.y - b2f(h.y));
  h.z = f2b(v.z); l.z = f2b(v.z - b2f(h.z));
  h.w = f2b(v.w); l.w = f2b(v.w - b2f(h.w));
  ((ushort4*)hi)[i] = h;
  ((ushort4*)lo)[i] = l;
}

// ---- transpose weights [K][N] (f32 or bf16 per flag) -> BT [N][K] bf16 ----
__global__ __launch_bounds__(256) void transpose_bf16_k(const void* __restrict__ B, long boff,
                                                        u16* __restrict__ BT, int K, int N,
                                                        const int* __restrict__ dflag) {
  int isf = dflag[0];
  __shared__ u16 tile[32][33];
  int n0 = blockIdx.x * 32, k0 = blockIdx.y * 32;
  int tx = threadIdx.x & 31, ty = threadIdx.x >> 5;
#pragma unroll
  for (int j = 0; j < 32; j += 8) {
    long idx = boff + (long)(k0 + ty + j) * N + n0 + tx;
    u16 uv = isf ? f2b(((const float*)B)[idx]) : ((const u16*)B)[idx];
    tile[ty + j][tx] = uv;
  }
  __syncthreads();
#pragma unroll
  for (int j = 0; j < 32; j += 8)
    BT[(long)(n0 + ty + j) * K + k0 + tx] = tile[tx][ty + j];
}

// ---- MFMA GEMM (post-router MoE only): C[M][N] = (Ah+Al)[M][K] @ BT[N][K]^T
// m97-verified pattern: 128x128 tile, BK=32, 4 waves (2x2), 4x4 frags of 16x16x32 bf16,
// global_load_lds 16B linear staging (NO swizzle this round), split-A => 2 MFMA per frag.
// OP 1: pair(Ch,Cl) = split(gelu(val) * wfull[row*8+eidx]).  OP 2: C += val.
template <int OP>
__global__ __launch_bounds__(256) void mfma_gemm_k(
    const u16* __restrict__ Ah, const u16* __restrict__ Al, const u16* __restrict__ BT,
    float* __restrict__ C, u16* __restrict__ Ch, u16* __restrict__ Cl,
    const float* __restrict__ wfull, int eidx, int M, int N, int K) {
  __shared__ __align__(16) u16 sAh[128 * 32];
  __shared__ __align__(16) u16 sAl[128 * 32];
  __shared__ __align__(16) u16 sBT[128 * 32];
  int t = threadIdx.x;
  int m0 = blockIdx.y * 128, n0 = blockIdx.x * 128;
  int l = t & 63, w = t >> 6;
  int wm = w >> 1, wn = w & 1;
  int lr = l & 15, lg = l >> 4;

  f32x4 zero = {0.f, 0.f, 0.f, 0.f};
  f32x4 acc[4][4];
#pragma unroll
  for (int i = 0; i < 4; i++)
#pragma unroll
    for (int j = 0; j < 4; j++) acc[i][j] = zero;

  for (int k0 = 0; k0 < K; k0 += 32) {
    __syncthreads();
#pragma unroll
    for (int i = 0; i < 2; i++) {
      int s = i * 256 + t;
      int r = s >> 2, c = s & 3;
      long ao = (long)(m0 + r) * K + k0 + c * 8;
      gload16(Ah + ao, sAh + s * 8);
      gload16(Al + ao, sAl + s * 8);
      gload16(BT + (long)(n0 + r) * K + k0 + c * 8, sBT + s * 8);
    }
    __syncthreads();
    bf16x8 fah[4], fal[4], fbb[4];
#pragma unroll
    for (int f = 0; f < 4; f++) {
      int ra = wm * 64 + f * 16 + lr;
      fah[f] = *(const bf16x8*)(sAh + ra * 32 + lg * 8);
      fal[f] = *(const bf16x8*)(sAl + ra * 32 + lg * 8);
      int rb = wn * 64 + f * 16 + lr;
      fbb[f] = *(const bf16x8*)(sBT + rb * 32 + lg * 8);
    }
#pragma unroll
    for (int i = 0; i < 4; i++)
#pragma unroll
      for (int j = 0; j < 4; j++) {
        acc[i][j] = __builtin_amdgcn_mfma_f32_16x16x32_bf16(fah[i], fbb[j], acc[i][j], 0, 0, 0);
        acc[i][j] = __builtin_amdgcn_mfma_f32_16x16x32_bf16(fal[i], fbb[j], acc[i][j], 0, 0, 0);
      }
  }

  // C/D layout (m89-verified): col = lane&15, row = (lane>>4)*4 + reg
  int row0 = m0 + wm * 64, col0 = n0 + wn * 64;
#pragma unroll
  for (int i = 0; i < 4; i++) {
#pragma unroll
    for (int j = 0; j < 4; j++) {
#pragma unroll
      for (int q = 0; q < 4; q++) {
        int row = row0 + i * 16 + lg * 4 + q;
        int col = col0 + j * 16 + lr;
        long idx = (long)row * N + col;
        float val = acc[i][j][q];
        if constexpr (OP == 1) {
          float gv = gelu_f(val) * wfull[(long)row * 8 + eidx];
          u16 h = f2b(gv);
          Ch[idx] = h;
          Cl[idx] = f2b(gv - b2f(h));
        } else {
          C[idx] += val;
        }
      }
    }
  }
}

// ------------------------------- launcher -------------------------------
extern "C" void kernel_launch(void* const* d_in, const int* in_sizes, int n_in,
                              void* d_out, int out_size, void* d_ws, size_t ws_size,
                              hipStream_t stream) {
  (void)in_sizes; (void)n_in;
  const void* x = d_in[0];
  const void* Wq = d_in[1];
  const void* Wk = d_in[2];
  const void* Wv = d_in[3];
  const void* Wo = d_in[4];
  const void* gpre = d_in[5];
  const void* gpost = d_in[6];
  const void* gpm = d_in[7];
  const void* gpo = d_in[8];
  const void* Wr = d_in[9];
  const void* W1 = d_in[10];
  const void* W2 = d_in[11];

  // EXACT baseline workspace layout (85 MB, known to fit) with MoE-phase aliases.
  char* ws = (char*)d_ws;
  size_t off = 0;
  auto AL = [&](size_t b) { size_t o = off; off += (b + 255) & ~(size_t)255; return o; };
  const size_t oFlag = AL(16);
  const size_t oWf = AL((size_t)Sq * NE * 4);
  const size_t oHid = AL((size_t)Sq * FHid * 4);  // 32MB: MoE hid bf16 pair (hi 16MB + lo 16MB)
  const size_t oH2 = AL((size_t)Sq * Dm * 4);     // h2f
  const size_t oX2 = AL((size_t)Sq * Dm * 4);     // x2
  const size_t oMoe = AL((size_t)Sq * Dm * 4);    // moe f32 accumulator
  const size_t oAp = AL((size_t)Sq * Dm * 4);     // attnp -> (MoE) W2T bf16 [Dm][FHid] = 8MB
  const size_t oAt = AL((size_t)Sq * Dm * 4);     // attnf -> (MoE) W1T bf16 [FHid][Dm] = 8MB
  const size_t oVf = AL((size_t)Sq * HDim * 4);
  const size_t oKf = AL((size_t)Sq * HDim * 4);
  const size_t oQf = AL((size_t)Sq * Dm * 4);     // qf -> (MoE) h2 bf16 pair (hi 4MB + lo 4MB)
  const size_t oH1 = AL((size_t)Sq * Dm * 4);
  if (off > ws_size || out_size != Sq * Dm + Sq * NE) return;

  float* h1f = (float*)(ws + oH1);
  float* qf = (float*)(ws + oQf);
  float* kf = (float*)(ws + oKf);
  float* vf = (float*)(ws + oVf);
  float* attnf = (float*)(ws + oAt);
  float* attnp = (float*)(ws + oAp);
  float* x2 = (float*)(ws + oX2);
  float* h2f = (float*)(ws + oH2);
  float* moe = (float*)(ws + oMoe);
  float* wfull = (float*)(ws + oWf);
  int* dflag = (int*)(ws + oFlag);
  // MoE-phase aliases (all source buffers dead by then):
  u16* hidh = (u16*)(ws + oHid);
  u16* hidl = hidh + (size_t)Sq * FHid;
  u16* bt1 = (u16*)(ws + oAt);  // W1T  (attnf dead after Wo GEMM)
  u16* bt2 = (u16*)(ws + oAp);  // W2T  (attnp dead after step-5 rmsnorm)
  u16* h2h = (u16*)(ws + oQf);  // h2 pair (qf dead after attention)
  u16* h2l = h2h + (size_t)Sq * Dm;
  float* out_x = (float*)d_out;
  float* out_probs = out_x + (size_t)Sq * Dm;

  // 0) dtype detect (inputs)
  detect_k<<<1, 256, 0, stream>>>((const u16*)x, dflag);

  // 1) h1 = rmsnorm(x, gpre) -> f32           [baseline-identical]
  rmsnorm2_k<1, 0><<<Sq, 64, 0, stream>>>(x, gpre, nullptr, h1f, dflag);

  // 2) projections                             [baseline-identical]
  gemm_nn_k<0><<<dim3(Dm / 64, Sq / 64), 256, 0, stream>>>(h1f, Wq, 0, qf, Sq, Dm, Dm, nullptr, 0, dflag);
  gemm_nn_k<0><<<dim3(HDim / 64, Sq / 64), 256, 0, stream>>>(h1f, Wk, 0, kf, Sq, HDim, Dm, nullptr, 0, dflag);
  gemm_nn_k<0><<<dim3(HDim / 64, Sq / 64), 256, 0, stream>>>(h1f, Wv, 0, vf, Sq, HDim, Dm, nullptr, 0, dflag);

  // 3) attention -> f32                        [baseline-identical]
  attn_f32_k<<<dim3(Sq / 64, NH), 256, 0, stream>>>(qf, kf, vf, attnf);

  // 4) attnp = attn @ Wo                       [baseline-identical]
  gemm_nn_k<0><<<dim3(Dm / 64, Sq / 64), 256, 0, stream>>>(attnf, Wo, 0, attnp, Sq, Dm, Dm, nullptr, 0, dflag);

  // 5) x2 = x + rmsnorm(attnp, gpost); h2 = rmsnorm(x2, gpm)   [baseline-identical]
  rmsnorm2_k<0, 2><<<Sq, 64, 0, stream>>>(attnp, gpost, x, x2, dflag);
  rmsnorm2_k<0, 0><<<Sq, 64, 0, stream>>>(x2, gpm, nullptr, h2f, dflag);

  // 6) router -> probs + dense top-2 weights   [baseline-identical => selections identical]
  router2_k<<<Sq / 256, 256, 0, stream>>>(h2f, Wr, out_probs, wfull, dflag);

  // 6.5) h2 hi/lo pair for MFMA MoE (post-router: no selection sensitivity)
  split_pair_k<<<(Sq * Dm / 4 + 255) / 256, 256, 0, stream>>>(h2f, h2h, h2l, Sq * Dm / 4);

  // 7) dense MoE via MFMA, expert by expert:
  //    hid' = w_e * gelu(h2 @ W1[e]) stored as bf16 pair; moe += hid' @ W2[e]
  hipMemsetAsync(ws + oMoe, 0, (size_t)Sq * Dm * 4, stream);
  for (int e = 0; e < NE; e++) {
    transpose_bf16_k<<<dim3(FHid / 32, Dm / 32), 256, 0, stream>>>(
        W1, (long)e * Dm * FHid, bt1, Dm, FHid, dflag);
    mfma_gemm_k<1><<<dim3(FHid / 128, Sq / 128), 256, 0, stream>>>(
        h2h, h2l, bt1, nullptr, hidh, hidl, wfull, e, Sq, FHid, Dm);
    transpose_bf16_k<<<dim3(Dm / 32, FHid / 32), 256, 0, stream>>>(
        W2, (long)e * FHid * Dm, bt2, FHid, Dm, dflag);
    mfma_gemm_k<2><<<dim3(Dm / 128, Sq / 128), 256, 0, stream>>>(
        hidh, hidl, bt2, moe, nullptr, nullptr, nullptr, 0, Sq, Dm, FHid);
  }

  // 8) out = x2 + rmsnorm(moe, gpo) -> FLOAT32 to d_out   [baseline-identical]
  rmsnorm2_k<0, 1><<<Sq, 64, 0, stream>>>(moe, gpo, x2, out_x, dflag);
}

// Round 4
// 2487.775 us; speedup vs baseline: 4.7358x; 1.8295x over previous
//
#include <hip/hip_runtime.h>

typedef unsigned short u16;

#define DEVFN static __device__ __forceinline__

constexpr int Sq = 2048, Dm = 1024, NH = 16, HDim = 64, NE = 8, FHid = 4096;

typedef __attribute__((ext_vector_type(8))) short bf16x8;
typedef __attribute__((ext_vector_type(4))) float f32x4;

DEVFN float b2f(u16 u) { return __uint_as_float(((unsigned)u) << 16); }
// round-to-nearest-even f32 -> bf16
DEVFN u16 f2b(float f) {
  unsigned u = __float_as_uint(f);
  return (u16)((u + 0x7fffu + ((u >> 16) & 1u)) >> 16);
}
DEVFN float gelu_f(float x) {
  float y = 0.7978845608028654f * (x + 0.044715f * x * x * x);
  float t = 1.0f - 2.0f / (__expf(2.0f * y) + 1.0f);
  return 0.5f * x * (1.0f + t);
}

DEVFN void gload16(const u16* g, u16* l) {
  __builtin_amdgcn_global_load_lds((const __attribute__((address_space(1))) void*)g,
                                   (__attribute__((address_space(3))) void*)l, 16, 0, 0);
}

// ---------------- input dtype detector: flag=1 if inputs are f32 ----------------
__global__ __launch_bounds__(256) void detect_k(const u16* __restrict__ x, int* __restrict__ flag) {
  int t = threadIdx.x;
  float mx = 0.f;
  for (int i = t; i < 4096; i += 256) mx = fmaxf(mx, fabsf(b2f(x[i])));
#pragma unroll
  for (int m = 32; m; m >>= 1) mx = fmaxf(mx, __shfl_xor(mx, m, 64));
  __shared__ float red[4];
  if ((t & 63) == 0) red[t >> 6] = mx;
  __syncthreads();
  if (t == 0) {
    float m2 = fmaxf(fmaxf(red[0], red[1]), fmaxf(red[2], red[3]));
    flag[0] = (m2 > 1e6f) ? 1 : 0;
  }
}

// ---- rmsnorm: ONE WAVE per row, shuffle reduction.  (VERBATIM baseline)
template <int INM, int RESM>
__global__ __launch_bounds__(64) void rmsnorm2_k(const void* __restrict__ inp, const void* __restrict__ g,
                                                 const void* __restrict__ resp, float* __restrict__ out1,
                                                 const int* __restrict__ dflag) {
  int isf = dflag[0];
  int row = blockIdx.x, t = threadIdx.x;  // 64 threads
  long rb = (long)row * Dm;
  float v[16];
#pragma unroll
  for (int j = 0; j < 4; j++) {
    long o = rb + t * 4 + j * 256;
    if (INM == 0 || isf) {
      float4 f = *((const float4*)((const float*)inp + o));
      v[4 * j] = f.x; v[4 * j + 1] = f.y; v[4 * j + 2] = f.z; v[4 * j + 3] = f.w;
    } else {
      ushort4 u = *((const ushort4*)((const u16*)inp + o));
      v[4 * j] = b2f(u.x); v[4 * j + 1] = b2f(u.y); v[4 * j + 2] = b2f(u.z); v[4 * j + 3] = b2f(u.w);
    }
  }
  float ss = 0.f;
#pragma unroll
  for (int j = 0; j < 16; j++) ss += v[j] * v[j];
#pragma unroll
  for (int m = 32; m; m >>= 1) ss += __shfl_xor(ss, m, 64);
  float sc = rsqrtf(ss * (1.0f / Dm) + 1e-5f);
#pragma unroll
  for (int j = 0; j < 4; j++) {
    long o = rb + t * 4 + j * 256;
    int go = t * 4 + j * 256;
    float gf[4];
    if (isf) {
      float4 gv = *((const float4*)((const float*)g + go));
      gf[0] = gv.x; gf[1] = gv.y; gf[2] = gv.z; gf[3] = gv.w;
    } else {
      ushort4 gu = *((const ushort4*)((const u16*)g + go));
      gf[0] = b2f(gu.x); gf[1] = b2f(gu.y); gf[2] = b2f(gu.z); gf[3] = b2f(gu.w);
    }
    float o4[4];
#pragma unroll
    for (int q = 0; q < 4; q++) o4[q] = v[4 * j + q] * sc * gf[q];
    if constexpr (RESM == 1) {
      float4 rf = *((const float4*)((const float*)resp + o));
      o4[0] += rf.x; o4[1] += rf.y; o4[2] += rf.z; o4[3] += rf.w;
    } else if constexpr (RESM == 2) {
      if (isf) {
        float4 rf = *((const float4*)((const float*)resp + o));
        o4[0] += rf.x; o4[1] += rf.y; o4[2] += rf.z; o4[3] += rf.w;
      } else {
        ushort4 ru = *((const ushort4*)((const u16*)resp + o));
        o4[0] += b2f(ru.x); o4[1] += b2f(ru.y); o4[2] += b2f(ru.z); o4[3] += b2f(ru.w);
      }
    }
    float4 of;
    of.x = o4[0]; of.y = o4[1]; of.z = o4[2]; of.w = o4[3];
    *((float4*)(out1 + o)) = of;
  }
}

// ---------------- naive tiled f32 GEMM (pre-router only; arithmetic VERBATIM baseline,
// LDS padding changed 17->20 / 65->68 for 16B row alignment — layout-only, bit-exact) ---
template <int OP>
__global__ __launch_bounds__(256) void gemm_nn_k(
    const float* __restrict__ A, const void* __restrict__ Braw, long boff,
    float* __restrict__ C, int M, int N, int K,
    const float* __restrict__ wfull, int eidx, const int* __restrict__ dflag) {
  int isf = dflag[0];
  const float* Bf = (const float*)Braw;
  const u16* Bh = (const u16*)Braw;
  int t = threadIdx.x;
  int m0 = blockIdx.y * 64, n0 = blockIdx.x * 64;

  __shared__ float As[64][20];
  __shared__ float Bs[16][68];

  int ty = t >> 4, tx = t & 15;
  float acc[4][4];
#pragma unroll
  for (int i = 0; i < 4; i++)
#pragma unroll
    for (int j = 0; j < 4; j++) acc[i][j] = 0.f;

  for (int k0 = 0; k0 < K; k0 += 16) {
    __syncthreads();
#pragma unroll
    for (int i = 0; i < 4; i++) {
      int idx = t + i * 256;
      int ar = idx >> 4, ac = idx & 15;
      As[ar][ac] = A[(long)(m0 + ar) * K + k0 + ac];
      int br = idx >> 6, bc = idx & 63;
      long bi = boff + (long)(k0 + br) * N + n0 + bc;
      Bs[br][bc] = isf ? Bf[bi] : b2f(Bh[bi]);
    }
    __syncthreads();
#pragma unroll
    for (int kk = 0; kk < 16; kk++) {
      float a[4], b[4];
#pragma unroll
      for (int i = 0; i < 4; i++) a[i] = As[ty * 4 + i][kk];
#pragma unroll
      for (int j = 0; j < 4; j++) b[j] = Bs[kk][tx * 4 + j];
#pragma unroll
      for (int i = 0; i < 4; i++)
#pragma unroll
        for (int j = 0; j < 4; j++) acc[i][j] += a[i] * b[j];
    }
  }
#pragma unroll
  for (int i = 0; i < 4; i++) {
    int row = m0 + ty * 4 + i;
#pragma unroll
    for (int j = 0; j < 4; j++) {
      int col = n0 + tx * 4 + j;
      long cidx = (long)row * N + col;
      float val = acc[i][j];
      if constexpr (OP == 0) C[cidx] = val;
      else if constexpr (OP == 1) C[cidx] = gelu_f(val);
      else C[cidx] += wfull[(long)row * 8 + eidx] * val;
    }
  }
}

// ---------------- plain-f32 attention (arithmetic VERBATIM baseline;
// LDS padding 65->68 (16B-aligned rows) + float4 staging — layout-only, bit-exact) ----
__global__ __launch_bounds__(256) void attn_f32_k(
    const float* __restrict__ Qf, const float* __restrict__ Kf, const float* __restrict__ Vf,
    float* __restrict__ Of) {
  int qb = blockIdx.x, h = blockIdx.y;
  int t = threadIdx.x;
  int qr = t >> 2;
  int sub = t & 3;
  __shared__ float Ks[64][68];
  __shared__ float Vs[64][68];
  int qrow = qb * 64 + qr;
  const float* qp = Qf + (long)qrow * Dm + h * HDim + sub * 16;
  float qfr[16];
#pragma unroll
  for (int j = 0; j < 16; j += 4) {
    float4 v = *(const float4*)(qp + j);
    qfr[j] = v.x; qfr[j + 1] = v.y; qfr[j + 2] = v.z; qfr[j + 3] = v.w;
  }
  float o[16];
#pragma unroll
  for (int j = 0; j < 16; j++) o[j] = 0.f;
  float m_i = -3e38f, l_i = 0.f;

  for (int kb = 0; kb < Sq / 64; kb++) {
    __syncthreads();
#pragma unroll
    for (int i = 0; i < 2; i++) {
      int idx = t + i * 256;
      int r = idx >> 3, c8 = (idx & 7) * 8;
      const float* kp = Kf + (long)(kb * 64 + r) * HDim + c8;
      float4 a = *(const float4*)(kp);
      float4 b = *(const float4*)(kp + 4);
      *(float4*)&Ks[r][c8] = a;
      *(float4*)&Ks[r][c8 + 4] = b;
      const float* vp = Vf + (long)(kb * 64 + r) * HDim + c8;
      float4 c = *(const float4*)(vp);
      float4 d = *(const float4*)(vp + 4);
      *(float4*)&Vs[r][c8] = c;
      *(float4*)&Vs[r][c8 + 4] = d;
    }
    __syncthreads();
    float s[64];
#pragma unroll
    for (int j = 0; j < 64; j++) {
      float acc = 0.f;
#pragma unroll
      for (int d = 0; d < 16; d++) acc += qfr[d] * Ks[j][sub * 16 + d];
      s[j] = acc;
    }
#pragma unroll
    for (int j = 0; j < 64; j++) {
      float v = s[j];
      v += __shfl_xor(v, 1, 64);
      v += __shfl_xor(v, 2, 64);
      s[j] = v * 0.125f;
    }
    float mx = s[0];
#pragma unroll
    for (int j = 1; j < 64; j++) mx = fmaxf(mx, s[j]);
    float mn = fmaxf(m_i, mx);
    float alpha = __expf(m_i - mn);
    m_i = mn;
    float ps = 0.f;
#pragma unroll
    for (int j = 0; j < 64; j++) {
      s[j] = __expf(s[j] - mn);
      ps += s[j];
    }
    l_i = l_i * alpha + ps;
#pragma unroll
    for (int d = 0; d < 16; d++) o[d] *= alpha;
#pragma unroll
    for (int j = 0; j < 64; j++)
#pragma unroll
      for (int d = 0; d < 16; d++) o[d] += s[j] * Vs[j][sub * 16 + d];
  }
  float inv = 1.0f / l_i;
#pragma unroll
  for (int d = 0; d < 16; d++)
    Of[(long)qrow * Dm + h * HDim + sub * 16 + d] = o[d] * inv;
}

// ---- router: one thread per token; top-2 from logits (logit/probs/wfull arithmetic
// VERBATIM baseline). ADDED: per-expert compacted token lists (post-selection only).
__global__ __launch_bounds__(256) void router2_k(const float* __restrict__ h2, const void* __restrict__ Wr,
                                                 float* __restrict__ probs_out, float* __restrict__ wfull,
                                                 const int* __restrict__ dflag,
                                                 int* __restrict__ ecnt, int* __restrict__ elist) {
  int isf = dflag[0];
  int tok = blockIdx.x * 256 + threadIdx.x;
  if (tok >= Sq) return;
  const float* hrow = h2 + (long)tok * Dm;
  float acc[8] = {0, 0, 0, 0, 0, 0, 0, 0};
  for (int i = 0; i < Dm; i++) {
    float hv = hrow[i];
    if (isf) {
      const float* wr = (const float*)Wr + (long)i * 8;
#pragma unroll
      for (int e = 0; e < 8; e++) acc[e] += hv * wr[e];
    } else {
      const u16* wr = (const u16*)Wr + (long)i * 8;
#pragma unroll
      for (int e = 0; e < 8; e++) acc[e] += hv * b2f(wr[e]);
    }
  }
  int i1 = 0;
#pragma unroll
  for (int e = 1; e < 8; e++)
    if (acc[e] > acc[i1]) i1 = e;
  int i2 = (i1 == 0) ? 1 : 0;
#pragma unroll
  for (int e = 0; e < 8; e++)
    if (e != i1 && acc[e] > acc[i2]) i2 = e;
  float mx = acc[i1];
  float pr[8], s = 0.f;
#pragma unroll
  for (int e = 0; e < 8; e++) { pr[e] = expf(acc[e] - mx); s += pr[e]; }
  float inv = 1.0f / s;
#pragma unroll
  for (int e = 0; e < 8; e++) {
    float pe = pr[e] * inv;
    probs_out[(long)tok * 8 + e] = pe;
    wfull[(long)tok * 8 + e] = (e == i1 || e == i2) ? pe : 0.f;
  }
  // compaction (does not touch logits/probs/wfull values)
  int p1 = atomicAdd(&ecnt[i1], 1);
  elist[i1 * Sq + p1] = tok;
  int p2 = atomicAdd(&ecnt[i2], 1);
  elist[i2 * Sq + p2] = tok;
}

// ---- split f32 -> (hi, lo) bf16 pair (2^-16): MoE h2 (post-router) ----
__global__ __launch_bounds__(256) void split_pair_k(const float* __restrict__ in, u16* __restrict__ hi,
                                                    u16* __restrict__ lo, int n4) {
  int i = blockIdx.x * 256 + threadIdx.x;
  if (i >= n4) return;
  float4 v = ((const float4*)in)[i];
  ushort4 h, l;
  h.x = f2b(v.x); l.x = f2b(v.x - b2f(h.x));
  h.y = f2b(v.y); l.y = f2b(v.y - b2f(h.y));
  h.z = f2b(v.z); l.z = f2b(v.z - b2f(h.z));
  h.w = f2b(v.w); l.w = f2b(v.w - b2f(h.w));
  ((ushort4*)hi)[i] = h;
  ((ushort4*)lo)[i] = l;
}

// ---- transpose weights [K][N] (f32 or bf16 per flag) -> BT [N][K] bf16 ----
__global__ __launch_bounds__(256) void transpose_bf16_k(const void* __restrict__ B, long boff,
                                                        u16* __restrict__ BT, int K, int N,
                                                        const int* __restrict__ dflag) {
  int isf = dflag[0];
  __shared__ u16 tile[32][33];
  int n0 = blockIdx.x * 32, k0 = blockIdx.y * 32;
  int tx = threadIdx.x & 31, ty = threadIdx.x >> 5;
#pragma unroll
  for (int j = 0; j < 32; j += 8) {
    long idx = boff + (long)(k0 + ty + j) * N + n0 + tx;
    u16 uv = isf ? f2b(((const float*)B)[idx]) : ((const u16*)B)[idx];
    tile[ty + j][tx] = uv;
  }
  __syncthreads();
#pragma unroll
  for (int j = 0; j < 32; j += 8)
    BT[(long)(n0 + ty + j) * K + k0 + tx] = tile[tx][ty + j];
}

// ---- SPARSE MoE W1: hid'[r] = split(gelu((h2h+h2l)[tok(r)] @ W1T^T) * w), compacted rows.
// 128x128 tile, BK=32, 4 waves (2x2), 4x4 frags of 16x16x32 bf16 (round-2-proven geometry).
// A-rows gathered via elist; tile pad rows (>= cnt) stored as ZERO so W2 reads are clean.
__global__ __launch_bounds__(256) void moe_w1_k(
    const u16* __restrict__ Ah, const u16* __restrict__ Al, const u16* __restrict__ BT,
    u16* __restrict__ Ch, u16* __restrict__ Cl, const float* __restrict__ wfull,
    const int* __restrict__ elist, const int* __restrict__ ecnt, int eidx) {
  constexpr int N = FHid, K = Dm;
  int cnt = ecnt[eidx];
  int m0 = blockIdx.y * 128, n0 = blockIdx.x * 128;
  if (m0 >= cnt) return;
  __shared__ __align__(16) u16 sAh[128 * 32];
  __shared__ __align__(16) u16 sAl[128 * 32];
  __shared__ __align__(16) u16 sBT[128 * 32];
  __shared__ int sTok[128];
  int t = threadIdx.x;
  if (t < 128) {
    int r = m0 + t;
    sTok[t] = (r < cnt) ? elist[eidx * Sq + r] : elist[eidx * Sq];
  }
  int l = t & 63, w = t >> 6;
  int wm = w >> 1, wn = w & 1;
  int lr = l & 15, lg = l >> 4;

  f32x4 zero = {0.f, 0.f, 0.f, 0.f};
  f32x4 acc[4][4];
#pragma unroll
  for (int i = 0; i < 4; i++)
#pragma unroll
    for (int j = 0; j < 4; j++) acc[i][j] = zero;

  for (int k0 = 0; k0 < K; k0 += 32) {
    __syncthreads();  // first iter also orders sTok writes before reads
#pragma unroll
    for (int i = 0; i < 2; i++) {
      int s = i * 256 + t;
      int r = s >> 2, c = s & 3;
      long ao = (long)sTok[r] * K + k0 + c * 8;
      gload16(Ah + ao, sAh + s * 8);
      gload16(Al + ao, sAl + s * 8);
      gload16(BT + (long)(n0 + r) * K + k0 + c * 8, sBT + s * 8);
    }
    __syncthreads();
    bf16x8 fah[4], fal[4], fbb[4];
#pragma unroll
    for (int f = 0; f < 4; f++) {
      int ra = wm * 64 + f * 16 + lr;
      fah[f] = *(const bf16x8*)(sAh + ra * 32 + lg * 8);
      fal[f] = *(const bf16x8*)(sAl + ra * 32 + lg * 8);
      int rb = wn * 64 + f * 16 + lr;
      fbb[f] = *(const bf16x8*)(sBT + rb * 32 + lg * 8);
    }
#pragma unroll
    for (int i = 0; i < 4; i++)
#pragma unroll
      for (int j = 0; j < 4; j++) {
        acc[i][j] = __builtin_amdgcn_mfma_f32_16x16x32_bf16(fah[i], fbb[j], acc[i][j], 0, 0, 0);
        acc[i][j] = __builtin_amdgcn_mfma_f32_16x16x32_bf16(fal[i], fbb[j], acc[i][j], 0, 0, 0);
      }
  }

  // C/D layout: col = lane&15, row = (lane>>4)*4 + reg
#pragma unroll
  for (int i = 0; i < 4; i++) {
#pragma unroll
    for (int j = 0; j < 4; j++) {
#pragma unroll
      for (int q = 0; q < 4; q++) {
        int widx = wm * 64 + i * 16 + lg * 4 + q;  // tile-local compacted row
        int col = n0 + wn * 64 + j * 16 + lr;
        bool valid = (m0 + widx) < cnt;
        int tok = sTok[widx];
        float gv = valid ? gelu_f(acc[i][j][q]) * wfull[(long)tok * 8 + eidx] : 0.f;
        u16 hh = f2b(gv);
        long idx = (long)(m0 + widx) * N + col;
        Ch[idx] = hh;
        Cl[idx] = f2b(gv - b2f(hh));
      }
    }
  }
}

// ---- SPARSE MoE W2: moe[tok(r)] += (hidh+hidl)[r] @ W2T^T, split-K=4, atomicAdd scatter.
__global__ __launch_bounds__(256) void moe_w2_k(
    const u16* __restrict__ Ah, const u16* __restrict__ Al, const u16* __restrict__ BT,
    float* __restrict__ C, const int* __restrict__ elist, const int* __restrict__ ecnt, int eidx) {
  constexpr int N = Dm, K = FHid;
  int cnt = ecnt[eidx];
  int m0 = blockIdx.y * 128, n0 = blockIdx.x * 128;
  if (m0 >= cnt) return;
  int kbeg = blockIdx.z * (K / 4), kend = kbeg + K / 4;
  __shared__ __align__(16) u16 sAh[128 * 32];
  __shared__ __align__(16) u16 sAl[128 * 32];
  __shared__ __align__(16) u16 sBT[128 * 32];
  __shared__ int sTok[128];
  int t = threadIdx.x;
  if (t < 128) {
    int r = m0 + t;
    sTok[t] = (r < cnt) ? elist[eidx * Sq + r] : elist[eidx * Sq];
  }
  int l = t & 63, w = t >> 6;
  int wm = w >> 1, wn = w & 1;
  int lr = l & 15, lg = l >> 4;

  f32x4 zero = {0.f, 0.f, 0.f, 0.f};
  f32x4 acc[4][4];
#pragma unroll
  for (int i = 0; i < 4; i++)
#pragma unroll
    for (int j = 0; j < 4; j++) acc[i][j] = zero;

  for (int k0 = kbeg; k0 < kend; k0 += 32) {
    __syncthreads();
#pragma unroll
    for (int i = 0; i < 2; i++) {
      int s = i * 256 + t;
      int r = s >> 2, c = s & 3;
      long ao = (long)(m0 + r) * K + k0 + c * 8;  // hid is compacted: direct rows
      gload16(Ah + ao, sAh + s * 8);
      gload16(Al + ao, sAl + s * 8);
      gload16(BT + (long)(n0 + r) * K + k0 + c * 8, sBT + s * 8);
    }
    __syncthreads();
    bf16x8 fah[4], fal[4], fbb[4];
#pragma unroll
    for (int f = 0; f < 4; f++) {
      int ra = wm * 64 + f * 16 + lr;
      fah[f] = *(const bf16x8*)(sAh + ra * 32 + lg * 8);
      fal[f] = *(const bf16x8*)(sAl + ra * 32 + lg * 8);
      int rb = wn * 64 + f * 16 + lr;
      fbb[f] = *(const bf16x8*)(sBT + rb * 32 + lg * 8);
    }
#pragma unroll
    for (int i = 0; i < 4; i++)
#pragma unroll
      for (int j = 0; j < 4; j++) {
        acc[i][j] = __builtin_amdgcn_mfma_f32_16x16x32_bf16(fah[i], fbb[j], acc[i][j], 0, 0, 0);
        acc[i][j] = __builtin_amdgcn_mfma_f32_16x16x32_bf16(fal[i], fbb[j], acc[i][j], 0, 0, 0);
      }
  }

#pragma unroll
  for (int i = 0; i < 4; i++) {
#pragma unroll
    for (int j = 0; j < 4; j++) {
#pragma unroll
      for (int q = 0; q < 4; q++) {
        int widx = wm * 64 + i * 16 + lg * 4 + q;
        int col = n0 + wn * 64 + j * 16 + lr;
        if ((m0 + widx) < cnt) {
          int tok = sTok[widx];
          atomicAdd(&C[(long)tok * N + col], acc[i][j][q]);
        }
      }
    }
  }
}

// ------------------------------- launcher -------------------------------
extern "C" void kernel_launch(void* const* d_in, const int* in_sizes, int n_in,
                              void* d_out, int out_size, void* d_ws, size_t ws_size,
                              hipStream_t stream) {
  (void)in_sizes; (void)n_in;
  const void* x = d_in[0];
  const void* Wq = d_in[1];
  const void* Wk = d_in[2];
  const void* Wv = d_in[3];
  const void* Wo = d_in[4];
  const void* gpre = d_in[5];
  const void* gpost = d_in[6];
  const void* gpm = d_in[7];
  const void* gpo = d_in[8];
  const void* Wr = d_in[9];
  const void* W1 = d_in[10];
  const void* W2 = d_in[11];

  // EXACT round-2 workspace layout (~89 MB, proven), with phase aliases.
  char* ws = (char*)d_ws;
  size_t off = 0;
  auto AL = [&](size_t b) { size_t o = off; off += (b + 255) & ~(size_t)255; return o; };
  const size_t oFlag = AL(16);
  const size_t oWf = AL((size_t)Sq * NE * 4);
  const size_t oHid = AL((size_t)Sq * FHid * 4);  // 32MB: MoE hid bf16 pair
  const size_t oH2 = AL((size_t)Sq * Dm * 4);     // h2f
  const size_t oX2 = AL((size_t)Sq * Dm * 4);     // x2
  const size_t oMoe = AL((size_t)Sq * Dm * 4);    // moe f32 accumulator
  const size_t oAp = AL((size_t)Sq * Dm * 4);     // attnp -> (MoE) W2T bf16
  const size_t oAt = AL((size_t)Sq * Dm * 4);     // attnf -> (MoE) W1T bf16
  const size_t oVf = AL((size_t)Sq * HDim * 4);   // vf -> (MoE) ecnt + elist (post-attn)
  const size_t oKf = AL((size_t)Sq * HDim * 4);
  const size_t oQf = AL((size_t)Sq * Dm * 4);     // qf -> (MoE) h2 bf16 pair
  const size_t oH1 = AL((size_t)Sq * Dm * 4);
  if (off > ws_size || out_size != Sq * Dm + Sq * NE) return;

  float* h1f = (float*)(ws + oH1);
  float* qf = (float*)(ws + oQf);
  float* kf = (float*)(ws + oKf);
  float* vf = (float*)(ws + oVf);
  float* attnf = (float*)(ws + oAt);
  float* attnp = (float*)(ws + oAp);
  float* x2 = (float*)(ws + oX2);
  float* h2f = (float*)(ws + oH2);
  float* moe = (float*)(ws + oMoe);
  float* wfull = (float*)(ws + oWf);
  int* dflag = (int*)(ws + oFlag);
  // MoE-phase aliases (source buffers dead by then):
  u16* hidh = (u16*)(ws + oHid);
  u16* hidl = hidh + (size_t)Sq * FHid;
  u16* bt1 = (u16*)(ws + oAt);   // W1T (attnf dead after Wo GEMM)
  u16* bt2 = (u16*)(ws + oAp);   // W2T (attnp dead after step-5 rmsnorm)
  u16* h2h = (u16*)(ws + oQf);   // h2 pair (qf dead after attention)
  u16* h2l = h2h + (size_t)Sq * Dm;
  int* ecnt = (int*)(ws + oVf);        // 8 ints (vf dead after attention)
  int* elist = (int*)(ws + oVf + 256); // 8*2048 ints = 64KB (oVf = 512KB)
  float* out_x = (float*)d_out;
  float* out_probs = out_x + (size_t)Sq * Dm;

  // 0) dtype detect
  detect_k<<<1, 256, 0, stream>>>((const u16*)x, dflag);

  // 1) h1 = rmsnorm(x, gpre)                       [baseline-identical]
  rmsnorm2_k<1, 0><<<Sq, 64, 0, stream>>>(x, gpre, nullptr, h1f, dflag);

  // 2) projections                                 [baseline-identical arithmetic]
  gemm_nn_k<0><<<dim3(Dm / 64, Sq / 64), 256, 0, stream>>>(h1f, Wq, 0, qf, Sq, Dm, Dm, nullptr, 0, dflag);
  gemm_nn_k<0><<<dim3(HDim / 64, Sq / 64), 256, 0, stream>>>(h1f, Wk, 0, kf, Sq, HDim, Dm, nullptr, 0, dflag);
  gemm_nn_k<0><<<dim3(HDim / 64, Sq / 64), 256, 0, stream>>>(h1f, Wv, 0, vf, Sq, HDim, Dm, nullptr, 0, dflag);

  // 3) attention                                   [baseline-identical arithmetic]
  attn_f32_k<<<dim3(Sq / 64, NH), 256, 0, stream>>>(qf, kf, vf, attnf);

  // 4) attnp = attn @ Wo                           [baseline-identical arithmetic]
  gemm_nn_k<0><<<dim3(Dm / 64, Sq / 64), 256, 0, stream>>>(attnf, Wo, 0, attnp, Sq, Dm, Dm, nullptr, 0, dflag);

  // 5) x2 = x + rmsnorm(attnp, gpost); h2 = rmsnorm(x2, gpm)   [baseline-identical]
  rmsnorm2_k<0, 2><<<Sq, 64, 0, stream>>>(attnp, gpost, x, x2, dflag);
  rmsnorm2_k<0, 0><<<Sq, 64, 0, stream>>>(x2, gpm, nullptr, h2f, dflag);

  // 6) router (+ compaction lists)                 [selection arithmetic baseline-identical]
  hipMemsetAsync(ws + oVf, 0, 32, stream);  // zero ecnt
  router2_k<<<Sq / 256, 256, 0, stream>>>(h2f, Wr, out_probs, wfull, dflag, ecnt, elist);

  // 7) h2 hi/lo pair for MFMA MoE
  split_pair_k<<<(Sq * Dm / 4 + 255) / 256, 256, 0, stream>>>(h2f, h2h, h2l, Sq * Dm / 4);

  // 8) SPARSE MoE: per expert, only its ~Sq*2/NE routed tokens (4x FLOP cut vs dense)
  hipMemsetAsync(ws + oMoe, 0, (size_t)Sq * Dm * 4, stream);
  for (int e = 0; e < NE; e++) {
    transpose_bf16_k<<<dim3(FHid / 32, Dm / 32), 256, 0, stream>>>(
        W1, (long)e * Dm * FHid, bt1, Dm, FHid, dflag);
    moe_w1_k<<<dim3(FHid / 128, Sq / 128), 256, 0, stream>>>(
        h2h, h2l, bt1, hidh, hidl, wfull, elist, ecnt, e);
    transpose_bf16_k<<<dim3(Dm / 32, FHid / 32), 256, 0, stream>>>(
        W2, (long)e * FHid * Dm, bt2, FHid, Dm, dflag);
    moe_w2_k<<<dim3(Dm / 128, Sq / 128, 4), 256, 0, stream>>>(
        hidh, hidl, bt2, moe, elist, ecnt, e);
  }

  // 9) out = x2 + rmsnorm(moe, gpo)                [baseline-identical]
  rmsnorm2_k<0, 1><<<Sq, 64, 0, stream>>>(moe, gpo, x2, out_x, dflag);
}